// Round 4
// baseline (195.266 us; speedup 1.0000x reference)
//
#include <hip/hip_runtime.h>
#include <float.h>
#include <stdint.h>

// SOM2D argmin ||x-w||^2 via split-f16 MFMA. N=32768, M=4096, D=128.
//
// score = ||w||^2 - 2 x.w   (||x||^2 dropped: constant per sample)
// cross = xh*wh + xl*wh + xh*wl  (f16 hi/lo split, fp32 accum; |err| ~2e-5)
//
// Round-4 design:
//  - prep kernel: W -> frag-major f16 hi/lo arrays in ws (2 MB, L2-resident)
//    + wsq, one pass. Main loop has ZERO conversion VALU, ZERO LDS, ZERO
//    barriers: B-frags load coalesced (base + lane*16) straight from L2.
//  - main: one wave owns 32 samples (A-frags hi+lo = 64 VGPRs resident,
//    acc = 32 -> ~160 total, no spill). Wave scans M/2 units, per-lane
//    running argmin, shuffle-reduce, writes packed (distbits|idx) u64
//    partial per unit-group. 512 blocks = 2/CU.
//  - finalize: min over the 2 partials -> grid labels.

constexpr int D = 128;

typedef _Float16 f16x8 __attribute__((ext_vector_type(8)));
typedef float    f32x4 __attribute__((ext_vector_type(4)));

__device__ __forceinline__ void cvt_split(const float4& a0, const float4& a1,
                                          f16x8& h, f16x8& l) {
    float v[8] = {a0.x, a0.y, a0.z, a0.w, a1.x, a1.y, a1.z, a1.w};
#pragma unroll
    for (int j = 0; j < 8; ++j) {
        _Float16 hh = (_Float16)v[j];
        h[j] = hh;
        l[j] = (_Float16)(v[j] - (float)hh);
    }
}

// W (M x D fp32) -> frag-major hi/lo f16 + wsq. Thread = (unit u, k-octet o).
// Frag-major slot for element block (u, k=8o..8o+7):
//   T=u>>6, t=(u>>4)&3, c=u&15, s=o>>2, q=o&3
//   slot = ((T*16 + s*4 + t) * 64) + q*16 + c     (f16x8 granules)
__global__ __launch_bounds__(256) void prep_kernel(
        const float* __restrict__ w, f16x8* __restrict__ hG,
        f16x8* __restrict__ lG, float* __restrict__ wsq, int M) {
    int g = blockIdx.x * 256 + threadIdx.x;
    if (g >= M * 16) return;
    int u = g >> 4, o = g & 15;
    const float4* wp = reinterpret_cast<const float4*>(w + (size_t)u * D + o * 8);
    float4 a0 = wp[0], a1 = wp[1];
    f16x8 h, l;
    cvt_split(a0, a1, h, l);
    float ss = 0.f;
    ss = fmaf(a0.x, a0.x, ss); ss = fmaf(a0.y, a0.y, ss);
    ss = fmaf(a0.z, a0.z, ss); ss = fmaf(a0.w, a0.w, ss);
    ss = fmaf(a1.x, a1.x, ss); ss = fmaf(a1.y, a1.y, ss);
    ss = fmaf(a1.z, a1.z, ss); ss = fmaf(a1.w, a1.w, ss);
#pragma unroll
    for (int m = 1; m < 16; m <<= 1) ss += __shfl_xor(ss, m, 64);
    if (o == 0) wsq[u] = ss;
    int slot = (((u >> 6) * 16 + (o >> 2) * 4 + ((u >> 4) & 3)) << 6)
             + ((o & 3) << 4) + (u & 15);
    hG[slot] = h;
    lG[slot] = l;
}

__global__ void finalize(const unsigned long long* __restrict__ keys,
                         const int* __restrict__ grid, int* __restrict__ out, int N) {
    int s = blockIdx.x * blockDim.x + threadIdx.x;
    if (s >= N) return;
    unsigned long long k0 = keys[s];
    unsigned long long k1 = keys[(size_t)N + s];
    unsigned long long k = k1 < k0 ? k1 : k0;   // equal dist -> lower idx (smaller key)
    int idx = (int)(unsigned)(k & 0xFFFFFFFFull);
    out[2 * s]     = grid[2 * idx];
    out[2 * s + 1] = grid[2 * idx + 1];
}

template <bool PARTIAL>
__global__ __launch_bounds__(256, 2) void som_main(
        const float* __restrict__ x, const f16x8* __restrict__ hG,
        const f16x8* __restrict__ lG, const float* __restrict__ wsq,
        const int* __restrict__ grid, int* __restrict__ out,
        unsigned long long* __restrict__ keys,
        int unitGroups, int M, int N) {
    const int tid  = threadIdx.x;
    const int lane = tid & 63;
    const int wv   = tid >> 6;
    const int c    = lane & 15;   // frag col-class
    const int q    = lane >> 4;   // frag quad

    const int ug    = blockIdx.x % unitGroups;
    const int sg    = blockIdx.x / unitGroups;
    const int sWave = sg * 128 + wv * 32;   // this wave's 32 samples

    // ---- A-frags: 32 samples x K=128, hi+lo, resident (64 VGPRs) ----
    // A[m = lane&15][k = q*8 + j], m-tile i in {0,1}, k-step s in 0..3.
    f16x8 Ah[8], Al[8];
#pragma unroll
    for (int i = 0; i < 2; ++i) {
        const float* xr = x + (size_t)(sWave + 16 * i + c) * D + q * 8;
#pragma unroll
        for (int s = 0; s < 4; ++s) {
            float4 a0 = *reinterpret_cast<const float4*>(xr + 32 * s);
            float4 a1 = *reinterpret_cast<const float4*>(xr + 32 * s + 4);
            cvt_split(a0, a1, Ah[i * 4 + s], Al[i * 4 + s]);
        }
    }

    float bestD[8];
    int   bestI[8];
#pragma unroll
    for (int sl = 0; sl < 8; ++sl) { bestD[sl] = FLT_MAX; bestI[sl] = 0; }

    const int tilesPer = (M / 64) / unitGroups;
    const int tile0    = ug * tilesPer;

    for (int tt = 0; tt < tilesPer; ++tt) {
        const int tile = tile0 + tt;
        const f16x8* hp = hG + ((size_t)tile << 10) + lane;   // tile*16*64
        const f16x8* lp = lG + ((size_t)tile << 10) + lane;

        f32x4 acc[8];
#pragma unroll
        for (int f = 0; f < 8; ++f) acc[f] = (f32x4){0.f, 0.f, 0.f, 0.f};

#pragma unroll
        for (int s = 0; s < 4; ++s) {
            f16x8 bh[4], bl[4];
#pragma unroll
            for (int t = 0; t < 4; ++t) {
                bh[t] = hp[(size_t)(s * 4 + t) << 6];
                bl[t] = lp[(size_t)(s * 4 + t) << 6];
            }
            // pass 1: xh.wh
#pragma unroll
            for (int i = 0; i < 2; ++i)
#pragma unroll
                for (int t = 0; t < 4; ++t)
                    acc[i * 4 + t] = __builtin_amdgcn_mfma_f32_16x16x32_f16(
                        Ah[i * 4 + s], bh[t], acc[i * 4 + t], 0, 0, 0);
            // pass 2: xl.wh
#pragma unroll
            for (int i = 0; i < 2; ++i)
#pragma unroll
                for (int t = 0; t < 4; ++t)
                    acc[i * 4 + t] = __builtin_amdgcn_mfma_f32_16x16x32_f16(
                        Al[i * 4 + s], bh[t], acc[i * 4 + t], 0, 0, 0);
            // pass 3: xh.wl
#pragma unroll
            for (int i = 0; i < 2; ++i)
#pragma unroll
                for (int t = 0; t < 4; ++t)
                    acc[i * 4 + t] = __builtin_amdgcn_mfma_f32_16x16x32_f16(
                        Ah[i * 4 + s], bl[t], acc[i * 4 + t], 0, 0, 0);
        }

        // ---- score + per-lane argmin. C layout: row m = q*4+r (+16i), col = c (+16t).
        const int uTile = tile * 64;
#pragma unroll
        for (int t = 0; t < 4; ++t) {
            const int n    = uTile + 16 * t + c;
            const float wq = wsq[n];
#pragma unroll
            for (int i = 0; i < 2; ++i) {
                f32x4 a = acc[i * 4 + t];
#pragma unroll
                for (int r = 0; r < 4; ++r) {
                    float score = fmaf(-2.f, a[r], wq);
                    int sl = i * 4 + r;
                    if (score < bestD[sl]) { bestD[sl] = score; bestI[sl] = n; }
                }
            }
        }
    }

    // ---- reduce over the 16 col-classes (within each q-group of 16 lanes) ----
#pragma unroll
    for (int sl = 0; sl < 8; ++sl) {
        float d   = bestD[sl];
        int   idx = bestI[sl];
#pragma unroll
        for (int m = 1; m < 16; m <<= 1) {
            float od = __shfl_xor(d, m, 64);
            int   oi = __shfl_xor(idx, m, 64);
            if (od < d || (od == d && oi < idx)) { d = od; idx = oi; }
        }
        if (c == 0) {
            const int sOut = sWave + 16 * (sl >> 2) + 4 * q + (sl & 3);
            if (PARTIAL) {
                unsigned ub = __float_as_uint(d);
                ub = (ub & 0x80000000u) ? ~ub : (ub | 0x80000000u);  // monotone map
                unsigned long long key = ((unsigned long long)ub << 32) | (unsigned)idx;
                keys[(size_t)ug * N + sOut] = key;
            } else {
                out[2 * sOut]     = grid[2 * idx];
                out[2 * sOut + 1] = grid[2 * idx + 1];
            }
        }
    }
}

extern "C" void kernel_launch(void* const* d_in, const int* in_sizes, int n_in,
                              void* d_out, int out_size, void* d_ws, size_t ws_size,
                              hipStream_t stream) {
    const float* x    = (const float*)d_in[0];
    const float* w    = (const float*)d_in[1];
    const int*   grid = (const int*)d_in[2];
    int* out = (int*)d_out;

    const int N = in_sizes[0] / D;   // 32768
    const int M = in_sizes[1] / D;   // 4096

    // ws layout: hG (M*D*2B) | lG (M*D*2B) | wsq (M*4B) | keys (2*N*8B)
    const size_t hlBytes   = (size_t)M * D * 2;          // per array
    const size_t baseBytes = 2 * hlBytes + (size_t)M * 4;
    const size_t keysBytes = 2 * (size_t)N * 8;

    f16x8* hG  = (f16x8*)d_ws;
    f16x8* lG  = (f16x8*)((char*)d_ws + hlBytes);
    float* wsq = (float*)((char*)d_ws + 2 * hlBytes);
    unsigned long long* keys = (unsigned long long*)((char*)d_ws + baseBytes);

    prep_kernel<<<(M * 16 + 255) / 256, 256, 0, stream>>>(w, hG, lG, wsq, M);

    const int sampleGroups = N / 128;   // 256 blocks of 4 waves x 32 samples
    if (ws_size >= baseBytes + keysBytes) {
        const int UG = 2;               // 512 blocks = 2/CU
        som_main<true><<<sampleGroups * UG, 256, 0, stream>>>(
            x, hG, lG, wsq, grid, out, keys, UG, M, N);
        finalize<<<(N + 255) / 256, 256, 0, stream>>>(keys, grid, out, N);
    } else {
        som_main<false><<<sampleGroups, 256, 0, stream>>>(
            x, hG, lG, wsq, grid, out, nullptr, 1, M, N);
    }
}

// Round 5
// 168.543 us; speedup vs baseline: 1.1585x; 1.1585x over previous
//
#include <hip/hip_runtime.h>
#include <float.h>
#include <stdint.h>

// SOM2D argmin ||x-w||^2 via split-f16 MFMA. N=32768, M=4096, D=128.
//
// score = ||w||^2 - 2 x.w  (||x||^2 constant per sample: dropped)
// cross = xh*wh + xl*wh + xh*wl  (f16 hi/lo split, fp32 accum; |err|~2e-5)
//
// Round-5: raise arithmetic intensity per B-byte (the binder) by doubling the
// per-wave m-tile to 64 samples (A hi+lo = 128 VGPRs resident). n-tile = 32
// units (acc = 32 AGPRs). B streams straight from L2 (pre-split frag-major
// f16 hi/lo in ws; zero LDS, zero barriers, zero in-loop conversion).
// B-demand at full MFMA rate: ~35 B/cyc/CU (was ~70, at the vL1D ceiling).
// Grid: (N/256 sample-groups) x UG=4 unit-groups = 512 blocks = 2 waves/SIMD.

constexpr int D = 128;

typedef _Float16 f16x8 __attribute__((ext_vector_type(8)));
typedef float    f32x4 __attribute__((ext_vector_type(4)));

__device__ __forceinline__ void cvt_split(const float4& a0, const float4& a1,
                                          f16x8& h, f16x8& l) {
    float v[8] = {a0.x, a0.y, a0.z, a0.w, a1.x, a1.y, a1.z, a1.w};
#pragma unroll
    for (int j = 0; j < 8; ++j) {
        _Float16 hh = (_Float16)v[j];
        h[j] = hh;
        l[j] = (_Float16)(v[j] - (float)hh);
    }
}

// W (M x D fp32) -> frag-major hi/lo f16 + wsq. Thread = (unit u, k-octet o).
// Granule slot for (u, k=8o..8o+7), n-tile = 32 units:
//   T=u>>5, t=(u>>4)&1, c=u&15, s=o>>2, q=o&3
//   slot = T*512 + s*128 + t*64 + q*16 + c
// Main-loop read address: tile_base(T*512) + s*128 + t*64 + lane. Sequential.
__global__ __launch_bounds__(256) void prep_kernel(
        const float* __restrict__ w, f16x8* __restrict__ hG,
        f16x8* __restrict__ lG, float* __restrict__ wsq, int M) {
    int g = blockIdx.x * 256 + threadIdx.x;
    if (g >= M * 16) return;
    int u = g >> 4, o = g & 15;
    const float4* wp = reinterpret_cast<const float4*>(w + (size_t)u * D + o * 8);
    float4 a0 = wp[0], a1 = wp[1];
    f16x8 h, l;
    cvt_split(a0, a1, h, l);
    float ss = 0.f;
    ss = fmaf(a0.x, a0.x, ss); ss = fmaf(a0.y, a0.y, ss);
    ss = fmaf(a0.z, a0.z, ss); ss = fmaf(a0.w, a0.w, ss);
    ss = fmaf(a1.x, a1.x, ss); ss = fmaf(a1.y, a1.y, ss);
    ss = fmaf(a1.z, a1.z, ss); ss = fmaf(a1.w, a1.w, ss);
#pragma unroll
    for (int m = 1; m < 16; m <<= 1) ss += __shfl_xor(ss, m, 64);
    if (o == 0) wsq[u] = ss;
    int slot = ((u >> 5) << 9) + ((o >> 2) << 7) + (((u >> 4) & 1) << 6)
             + ((o & 3) << 4) + (u & 15);
    hG[slot] = h;
    lG[slot] = l;
}

__global__ void finalize(const unsigned long long* __restrict__ keys,
                         const int* __restrict__ grid, int* __restrict__ out,
                         int N, int UG) {
    int s = blockIdx.x * blockDim.x + threadIdx.x;
    if (s >= N) return;
    unsigned long long k = keys[s];
    for (int g = 1; g < UG; ++g) {
        unsigned long long kg = keys[(size_t)g * N + s];
        if (kg < k) k = kg;   // equal dist -> lower idx (smaller key)
    }
    int idx = (int)(unsigned)(k & 0xFFFFFFFFull);
    out[2 * s]     = grid[2 * idx];
    out[2 * s + 1] = grid[2 * idx + 1];
}

template <bool PARTIAL>
__global__ __launch_bounds__(256, 2) void som_main(
        const float* __restrict__ x, const f16x8* __restrict__ hG,
        const f16x8* __restrict__ lG, const float* __restrict__ wsq,
        const int* __restrict__ grid, int* __restrict__ out,
        unsigned long long* __restrict__ keys,
        int unitGroups, int M, int N) {
    const int tid  = threadIdx.x;
    const int lane = tid & 63;
    const int wv   = tid >> 6;
    const int c    = lane & 15;   // frag col-class
    const int q    = lane >> 4;   // frag quad

    const int ug    = blockIdx.x % unitGroups;
    const int sg    = blockIdx.x / unitGroups;
    const int sWave = sg * 256 + wv * 64;   // this wave's 64 samples

    // ---- A-frags: 64 samples x K=128, hi+lo, resident (128 VGPRs) ----
    // A[m = lane&15][k = q*8 + j], m-tile i in 0..3, k-step s in 0..3.
    f16x8 Ah[16], Al[16];
#pragma unroll
    for (int i = 0; i < 4; ++i) {
        const float* xr = x + (size_t)(sWave + 16 * i + c) * D + q * 8;
#pragma unroll
        for (int s = 0; s < 4; ++s) {
            float4 a0 = *reinterpret_cast<const float4*>(xr + 32 * s);
            float4 a1 = *reinterpret_cast<const float4*>(xr + 32 * s + 4);
            cvt_split(a0, a1, Ah[i * 4 + s], Al[i * 4 + s]);
        }
    }

    float bestD[16];
    int   bestI[16];
#pragma unroll
    for (int sl = 0; sl < 16; ++sl) { bestD[sl] = FLT_MAX; bestI[sl] = 0; }

    const int tilesPer = (M / 32) / unitGroups;
    const int tile0    = ug * tilesPer;

    for (int tt = 0; tt < tilesPer; ++tt) {
        const int tile = tile0 + tt;
        const f16x8* hp = hG + ((size_t)tile << 9) + lane;
        const f16x8* lp = lG + ((size_t)tile << 9) + lane;

        f32x4 acc[8];   // [i*2 + t]
#pragma unroll
        for (int f = 0; f < 8; ++f) acc[f] = (f32x4){0.f, 0.f, 0.f, 0.f};

#pragma unroll
        for (int s = 0; s < 4; ++s) {
            f16x8 bh[2], bl[2];
#pragma unroll
            for (int t = 0; t < 2; ++t) {
                bh[t] = hp[(size_t)(s * 128 + t * 64)];
                bl[t] = lp[(size_t)(s * 128 + t * 64)];
            }
            // pass 1: xh.wh
#pragma unroll
            for (int i = 0; i < 4; ++i)
#pragma unroll
                for (int t = 0; t < 2; ++t)
                    acc[i * 2 + t] = __builtin_amdgcn_mfma_f32_16x16x32_f16(
                        Ah[i * 4 + s], bh[t], acc[i * 2 + t], 0, 0, 0);
            // pass 2: xl.wh
#pragma unroll
            for (int i = 0; i < 4; ++i)
#pragma unroll
                for (int t = 0; t < 2; ++t)
                    acc[i * 2 + t] = __builtin_amdgcn_mfma_f32_16x16x32_f16(
                        Al[i * 4 + s], bh[t], acc[i * 2 + t], 0, 0, 0);
            // pass 3: xh.wl
#pragma unroll
            for (int i = 0; i < 4; ++i)
#pragma unroll
                for (int t = 0; t < 2; ++t)
                    acc[i * 2 + t] = __builtin_amdgcn_mfma_f32_16x16x32_f16(
                        Ah[i * 4 + s], bl[t], acc[i * 2 + t], 0, 0, 0);
        }

        // ---- score + per-lane argmin. C layout: row m = q*4+r (+16i), col = c (+16t).
        const int uTile = tile * 32;
#pragma unroll
        for (int t = 0; t < 2; ++t) {
            const int n    = uTile + 16 * t + c;
            const float wq = wsq[n];
#pragma unroll
            for (int i = 0; i < 4; ++i) {
                f32x4 a = acc[i * 2 + t];
#pragma unroll
                for (int r = 0; r < 4; ++r) {
                    float score = fmaf(-2.f, a[r], wq);
                    int sl = i * 4 + r;
                    if (score < bestD[sl]) { bestD[sl] = score; bestI[sl] = n; }
                }
            }
        }
    }

    // ---- reduce over the 16 col-classes (xor within each 16-lane q-group) ----
#pragma unroll
    for (int sl = 0; sl < 16; ++sl) {
        float d   = bestD[sl];
        int   idx = bestI[sl];
#pragma unroll
        for (int m = 1; m < 16; m <<= 1) {
            float od = __shfl_xor(d, m, 64);
            int   oi = __shfl_xor(idx, m, 64);
            if (od < d || (od == d && oi < idx)) { d = od; idx = oi; }
        }
        if (c == 0) {
            const int sOut = sWave + 16 * (sl >> 2) + 4 * q + (sl & 3);
            if (PARTIAL) {
                unsigned ub = __float_as_uint(d);
                ub = (ub & 0x80000000u) ? ~ub : (ub | 0x80000000u);  // monotone map
                unsigned long long key = ((unsigned long long)ub << 32) | (unsigned)idx;
                keys[(size_t)ug * N + sOut] = key;
            } else {
                out[2 * sOut]     = grid[2 * idx];
                out[2 * sOut + 1] = grid[2 * idx + 1];
            }
        }
    }
}

extern "C" void kernel_launch(void* const* d_in, const int* in_sizes, int n_in,
                              void* d_out, int out_size, void* d_ws, size_t ws_size,
                              hipStream_t stream) {
    const float* x    = (const float*)d_in[0];
    const float* w    = (const float*)d_in[1];
    const int*   grid = (const int*)d_in[2];
    int* out = (int*)d_out;

    const int N = in_sizes[0] / D;   // 32768
    const int M = in_sizes[1] / D;   // 4096

    // ws layout: hG (1 MB) | lG (1 MB) | wsq (16 KB) | keys (UG*N*8)
    const size_t hlBytes   = (size_t)M * D * 2;
    const size_t baseBytes = 2 * hlBytes + (size_t)M * 4;

    f16x8* hG  = (f16x8*)d_ws;
    f16x8* lG  = (f16x8*)((char*)d_ws + hlBytes);
    float* wsq = (float*)((char*)d_ws + 2 * hlBytes);
    unsigned long long* keys = (unsigned long long*)((char*)d_ws + baseBytes);

    prep_kernel<<<(M * 16 + 255) / 256, 256, 0, stream>>>(w, hG, lG, wsq, M);

    const int sampleGroups = N / 256;   // blocks of 4 waves x 64 samples
    int UG = 0;
    if (ws_size >= baseBytes + 4ull * N * 8) UG = 4;
    else if (ws_size >= baseBytes + 2ull * N * 8) UG = 2;

    if (UG > 0) {
        som_main<true><<<sampleGroups * UG, 256, 0, stream>>>(
            x, hG, lG, wsq, grid, out, keys, UG, M, N);
        finalize<<<(N + 255) / 256, 256, 0, stream>>>(keys, grid, out, N, UG);
    } else {
        som_main<false><<<sampleGroups, 256, 0, stream>>>(
            x, hG, lG, wsq, grid, out, nullptr, 1, M, N);
    }
}

// Round 6
// 153.642 us; speedup vs baseline: 1.2709x; 1.0970x over previous
//
#include <hip/hip_runtime.h>
#include <float.h>
#include <stdint.h>

// SOM2D argmin ||x-w||^2 via split-f16 MFMA. N=32768, M=4096, D=128.
//
// score = ||w||^2 - 2 x.w  (||x||^2 constant per sample: dropped)
// cross = xh*wh + xl*wh + xh*wl  (f16 hi/lo split, fp32 accum; |err|~2e-5)
//
// Round-6: fix the round-5 stall (B loads issued just-in-time inside the
// s-loop -> ~300cyc L2 latency exposed 4x per tile, MfmaUtil 38%). Now the
// FULL tile of B (16 granules, 64 VGPRs) is loaded before the 96-MFMA burst;
// latency exposed once per ~1862 cyc. To fund the extra 32 B-regs, Al (x-lo
// frags, pass-2 only) moves to wave-private LDS (4x16KB = 64KB/block, no
// barriers, conflict-free reads). ~220 regs/wave -> 2 waves/SIMD kept.

constexpr int D = 128;

typedef _Float16 f16x8 __attribute__((ext_vector_type(8)));
typedef float    f32x4 __attribute__((ext_vector_type(4)));

__device__ __forceinline__ void cvt_split(const float4& a0, const float4& a1,
                                          f16x8& h, f16x8& l) {
    float v[8] = {a0.x, a0.y, a0.z, a0.w, a1.x, a1.y, a1.z, a1.w};
#pragma unroll
    for (int j = 0; j < 8; ++j) {
        _Float16 hh = (_Float16)v[j];
        h[j] = hh;
        l[j] = (_Float16)(v[j] - (float)hh);
    }
}

// W (M x D fp32) -> frag-major hi/lo f16 + wsq. Thread = (unit u, k-octet o).
// Granule slot for (u, k=8o..8o+7), n-tile = 32 units:
//   T=u>>5, t=(u>>4)&1, c=u&15, s=o>>2, q=o&3
//   slot = T*512 + s*128 + t*64 + q*16 + c
// Main-loop read: tile_base(T*512) + s*128 + t*64 + lane. Sequential 1KB/instr.
__global__ __launch_bounds__(256) void prep_kernel(
        const float* __restrict__ w, f16x8* __restrict__ hG,
        f16x8* __restrict__ lG, float* __restrict__ wsq, int M) {
    int g = blockIdx.x * 256 + threadIdx.x;
    if (g >= M * 16) return;
    int u = g >> 4, o = g & 15;
    const float4* wp = reinterpret_cast<const float4*>(w + (size_t)u * D + o * 8);
    float4 a0 = wp[0], a1 = wp[1];
    f16x8 h, l;
    cvt_split(a0, a1, h, l);
    float ss = 0.f;
    ss = fmaf(a0.x, a0.x, ss); ss = fmaf(a0.y, a0.y, ss);
    ss = fmaf(a0.z, a0.z, ss); ss = fmaf(a0.w, a0.w, ss);
    ss = fmaf(a1.x, a1.x, ss); ss = fmaf(a1.y, a1.y, ss);
    ss = fmaf(a1.z, a1.z, ss); ss = fmaf(a1.w, a1.w, ss);
#pragma unroll
    for (int m = 1; m < 16; m <<= 1) ss += __shfl_xor(ss, m, 64);
    if (o == 0) wsq[u] = ss;
    int slot = ((u >> 5) << 9) + ((o >> 2) << 7) + (((u >> 4) & 1) << 6)
             + ((o & 3) << 4) + (u & 15);
    hG[slot] = h;
    lG[slot] = l;
}

__global__ void finalize(const unsigned long long* __restrict__ keys,
                         const int* __restrict__ grid, int* __restrict__ out,
                         int N, int UG) {
    int s = blockIdx.x * blockDim.x + threadIdx.x;
    if (s >= N) return;
    unsigned long long k = keys[s];
    for (int g = 1; g < UG; ++g) {
        unsigned long long kg = keys[(size_t)g * N + s];
        if (kg < k) k = kg;   // equal dist -> lower idx (smaller key)
    }
    int idx = (int)(unsigned)(k & 0xFFFFFFFFull);
    out[2 * s]     = grid[2 * idx];
    out[2 * s + 1] = grid[2 * idx + 1];
}

template <bool PARTIAL>
__global__ __launch_bounds__(256, 2) void som_main(
        const float* __restrict__ x, const f16x8* __restrict__ hG,
        const f16x8* __restrict__ lG, const float* __restrict__ wsq,
        const int* __restrict__ grid, int* __restrict__ out,
        unsigned long long* __restrict__ keys,
        int unitGroups, int M, int N) {
    // Al (x-lo A-frags), wave-private: wave wv owns albuf[wv*1024 .. +1024)
    __shared__ f16x8 albuf[4 * 1024];   // 64 KB

    const int tid  = threadIdx.x;
    const int lane = tid & 63;
    const int wv   = tid >> 6;
    const int c    = lane & 15;   // frag col-class
    const int q    = lane >> 4;   // frag quad

    const int ug    = blockIdx.x % unitGroups;
    const int sg    = blockIdx.x / unitGroups;
    const int sWave = sg * 256 + wv * 64;   // this wave's 64 samples

    f16x8* myAl = &albuf[wv * 1024];

    // ---- A-frags: 64 samples x K=128. Ah resident (64 VGPRs); Al -> LDS.
    // A[m = lane&15][k = q*8 + j], m-tile i in 0..3, k-step s in 0..3.
    f16x8 Ah[16];
#pragma unroll
    for (int i = 0; i < 4; ++i) {
        const float* xr = x + (size_t)(sWave + 16 * i + c) * D + q * 8;
#pragma unroll
        for (int s = 0; s < 4; ++s) {
            float4 a0 = *reinterpret_cast<const float4*>(xr + 32 * s);
            float4 a1 = *reinterpret_cast<const float4*>(xr + 32 * s + 4);
            f16x8 h, l;
            cvt_split(a0, a1, h, l);
            Ah[i * 4 + s] = h;
            myAl[(i * 4 + s) * 64 + lane] = l;   // own slice only: no barrier
        }
    }

    float bestD[16];
    int   bestI[16];
#pragma unroll
    for (int sl = 0; sl < 16; ++sl) { bestD[sl] = FLT_MAX; bestI[sl] = 0; }

    const int tilesPer = (M / 32) / unitGroups;
    const int tile0    = ug * tilesPer;

    for (int tt = 0; tt < tilesPer; ++tt) {
        const int tile = tile0 + tt;
        const f16x8* hp = hG + ((size_t)tile << 9) + lane;
        const f16x8* lp = lG + ((size_t)tile << 9) + lane;

        // ---- hoist the ENTIRE tile's B into registers before the MFMA burst.
        // bh first (pass 1+2 operands land first), then bl (pass 3).
        f16x8 bh[8], bl[8];
#pragma unroll
        for (int s = 0; s < 4; ++s)
#pragma unroll
            for (int t = 0; t < 2; ++t)
                bh[s * 2 + t] = hp[s * 128 + t * 64];
#pragma unroll
        for (int s = 0; s < 4; ++s)
#pragma unroll
            for (int t = 0; t < 2; ++t)
                bl[s * 2 + t] = lp[s * 128 + t * 64];

        const int uTile = tile * 32;
        const float wq0 = wsq[uTile + c];
        const float wq1 = wsq[uTile + 16 + c];

        f32x4 acc[8];   // [i*2 + t]
#pragma unroll
        for (int f = 0; f < 8; ++f) acc[f] = (f32x4){0.f, 0.f, 0.f, 0.f};

        // pass 1: xh.wh
#pragma unroll
        for (int s = 0; s < 4; ++s)
#pragma unroll
            for (int i = 0; i < 4; ++i)
#pragma unroll
                for (int t = 0; t < 2; ++t)
                    acc[i * 2 + t] = __builtin_amdgcn_mfma_f32_16x16x32_f16(
                        Ah[i * 4 + s], bh[s * 2 + t], acc[i * 2 + t], 0, 0, 0);
        // pass 2: xl.wh (Al from wave-private LDS; 4 ds_read_b128 per s)
#pragma unroll
        for (int s = 0; s < 4; ++s) {
            f16x8 al[4];
#pragma unroll
            for (int i = 0; i < 4; ++i) al[i] = myAl[(i * 4 + s) * 64 + lane];
#pragma unroll
            for (int i = 0; i < 4; ++i)
#pragma unroll
                for (int t = 0; t < 2; ++t)
                    acc[i * 2 + t] = __builtin_amdgcn_mfma_f32_16x16x32_f16(
                        al[i], bh[s * 2 + t], acc[i * 2 + t], 0, 0, 0);
        }
        // pass 3: xh.wl
#pragma unroll
        for (int s = 0; s < 4; ++s)
#pragma unroll
            for (int i = 0; i < 4; ++i)
#pragma unroll
                for (int t = 0; t < 2; ++t)
                    acc[i * 2 + t] = __builtin_amdgcn_mfma_f32_16x16x32_f16(
                        Ah[i * 4 + s], bl[s * 2 + t], acc[i * 2 + t], 0, 0, 0);

        // ---- score + per-lane argmin. C layout: row m = q*4+r (+16i), col = c (+16t).
#pragma unroll
        for (int t = 0; t < 2; ++t) {
            const int n    = uTile + 16 * t + c;
            const float wq = t == 0 ? wq0 : wq1;
#pragma unroll
            for (int i = 0; i < 4; ++i) {
                f32x4 a = acc[i * 2 + t];
#pragma unroll
                for (int r = 0; r < 4; ++r) {
                    float score = fmaf(-2.f, a[r], wq);
                    int sl = i * 4 + r;
                    if (score < bestD[sl]) { bestD[sl] = score; bestI[sl] = n; }
                }
            }
        }
    }

    // ---- reduce over the 16 col-classes (xor within each 16-lane q-group) ----
#pragma unroll
    for (int sl = 0; sl < 16; ++sl) {
        float d   = bestD[sl];
        int   idx = bestI[sl];
#pragma unroll
        for (int m = 1; m < 16; m <<= 1) {
            float od = __shfl_xor(d, m, 64);
            int   oi = __shfl_xor(idx, m, 64);
            if (od < d || (od == d && oi < idx)) { d = od; idx = oi; }
        }
        if (c == 0) {
            const int sOut = sWave + 16 * (sl >> 2) + 4 * q + (sl & 3);
            if (PARTIAL) {
                unsigned ub = __float_as_uint(d);
                ub = (ub & 0x80000000u) ? ~ub : (ub | 0x80000000u);  // monotone map
                unsigned long long key = ((unsigned long long)ub << 32) | (unsigned)idx;
                keys[(size_t)ug * N + sOut] = key;
            } else {
                out[2 * sOut]     = grid[2 * idx];
                out[2 * sOut + 1] = grid[2 * idx + 1];
            }
        }
    }
}

extern "C" void kernel_launch(void* const* d_in, const int* in_sizes, int n_in,
                              void* d_out, int out_size, void* d_ws, size_t ws_size,
                              hipStream_t stream) {
    const float* x    = (const float*)d_in[0];
    const float* w    = (const float*)d_in[1];
    const int*   grid = (const int*)d_in[2];
    int* out = (int*)d_out;

    const int N = in_sizes[0] / D;   // 32768
    const int M = in_sizes[1] / D;   // 4096

    // ws layout: hG (1 MB) | lG (1 MB) | wsq (16 KB) | keys (UG*N*8)
    const size_t hlBytes   = (size_t)M * D * 2;
    const size_t baseBytes = 2 * hlBytes + (size_t)M * 4;

    f16x8* hG  = (f16x8*)d_ws;
    f16x8* lG  = (f16x8*)((char*)d_ws + hlBytes);
    float* wsq = (float*)((char*)d_ws + 2 * hlBytes);
    unsigned long long* keys = (unsigned long long*)((char*)d_ws + baseBytes);

    prep_kernel<<<(M * 16 + 255) / 256, 256, 0, stream>>>(w, hG, lG, wsq, M);

    const int sampleGroups = N / 256;   // blocks of 4 waves x 64 samples
    int UG = 0;
    if (ws_size >= baseBytes + 4ull * N * 8) UG = 4;
    else if (ws_size >= baseBytes + 2ull * N * 8) UG = 2;

    if (UG > 0) {
        som_main<true><<<sampleGroups * UG, 256, 0, stream>>>(
            x, hG, lG, wsq, grid, out, keys, UG, M, N);
        finalize<<<(N + 255) / 256, 256, 0, stream>>>(keys, grid, out, N, UG);
    } else {
        som_main<false><<<sampleGroups, 256, 0, stream>>>(
            x, hG, lG, wsq, grid, out, nullptr, 1, M, N);
    }
}